// Round 1
// baseline (887.626 us; speedup 1.0000x reference)
//
#include <hip/hip_runtime.h>
#include <hip/hip_bf16.h>

#define N_NODES 50000
#define N_EDGES 800000
#define D_IN    128
#define D_H     64
#define SZ_C    4
#define D_ALL   (SZ_C * D_H)   // 256

// ---------------- setup kernels ----------------

__global__ void init_deg_kernel(int* __restrict__ deg_cnt, int* __restrict__ cursor, int n) {
    int i = blockIdx.x * blockDim.x + threadIdx.x;
    if (i < n) { deg_cnt[i] = 0; cursor[i] = 0; }
}

__global__ void hist_kernel(const int* __restrict__ dst, int* __restrict__ deg_cnt, int e) {
    int i = blockIdx.x * blockDim.x + threadIdx.x;
    if (i < e) atomicAdd(&deg_cnt[dst[i]], 1);
}

__global__ void dinv_kernel(const int* __restrict__ deg_cnt, float* __restrict__ dinv,
                            float* __restrict__ selfn, int n) {
    int i = blockIdx.x * blockDim.x + threadIdx.x;
    if (i < n) {
        float df = (float)deg_cnt[i] + 1.0f;
        float dv = rsqrtf(df);
        dinv[i] = dv;
        selfn[i] = dv * dv;
    }
}

// single-block exclusive scan: row_start[0]=0, row_start[i+1]=sum cnt[0..i]
__global__ void scan_kernel(const int* __restrict__ cnt, int* __restrict__ row_start, int n) {
    __shared__ int sdata[1024];
    __shared__ int s_running;
    int t = threadIdx.x;
    if (t == 0) { s_running = 0; row_start[0] = 0; }
    __syncthreads();
    for (int base = 0; base < n; base += 1024) {
        int v = (base + t < n) ? cnt[base + t] : 0;
        sdata[t] = v;
        __syncthreads();
        // Hillis-Steele inclusive scan (read, barrier, write, barrier)
        for (int off = 1; off < 1024; off <<= 1) {
            int x = (t >= off) ? sdata[t - off] : 0;
            __syncthreads();
            sdata[t] += x;
            __syncthreads();
        }
        int incl = sdata[t];
        int run = s_running;
        if (base + t < n) row_start[base + t + 1] = run + incl;
        __syncthreads();
        if (t == 0) s_running = run + sdata[1023];
        __syncthreads();
    }
}

__global__ void csr_build_kernel(const int* __restrict__ src, const int* __restrict__ dst,
                                 const int* __restrict__ row_start, int* __restrict__ cursor,
                                 const float* __restrict__ dinv,
                                 int* __restrict__ csr_src, float* __restrict__ csr_coef, int e) {
    int i = blockIdx.x * blockDim.x + threadIdx.x;
    if (i < e) {
        int d = dst[i];
        int s = src[i];
        int pos = row_start[d] + atomicAdd(&cursor[d], 1);
        csr_src[pos] = s;
        csr_coef[pos] = dinv[s] * dinv[d];
    }
}

// pack W0 [4,128,64] -> Wcat [128,256] row-major: Wcat[k*256 + c*64 + d] = W0[c*8192 + k*64 + d]
__global__ void pack_w_kernel(const float* __restrict__ W0, float* __restrict__ Wcat) {
    int tid = blockIdx.x * blockDim.x + threadIdx.x;  // 0..32767
    int k = tid >> 8;
    int r = tid & 255;
    int c = r >> 6;
    int d = r & 63;
    Wcat[tid] = W0[c * (D_IN * D_H) + k * D_H + d];
}

// ---------------- GEMM ----------------
// C[m, c*64+d] = sum_k A[m*lda + aChanOff*c + k] * B[bChanStride*c + k*ldb + d]
// grid: (ceil(M/64), 4), block 256. Tile 64x64, TK=32, 4x4 per thread.

__global__ __launch_bounds__(256) void gemm_kernel(
    const float* __restrict__ A, int lda, int aChanOff,
    const float* __restrict__ B, int ldb, int bChanStride,
    float* __restrict__ C, int M, int K)
{
    __shared__ float As[64][33];
    __shared__ float Bs[32][65];
    int c = blockIdx.y;
    int m0 = blockIdx.x * 64;
    const float* Ab = A + (size_t)aChanOff * c;
    const float* Bb = B + (size_t)bChanStride * c;
    int t = threadIdx.x;
    int tx = t & 15, ty = t >> 4;
    float acc[4][4] = {};
    for (int k0 = 0; k0 < K; k0 += 32) {
        int ar = t >> 5, akk = t & 31;
        #pragma unroll
        for (int i = 0; i < 8; ++i) {
            int r = ar + i * 8;
            int gm = m0 + r;
            As[r][akk] = (gm < M) ? Ab[(size_t)gm * lda + k0 + akk] : 0.f;
        }
        int br = t >> 6, bc = t & 63;
        #pragma unroll
        for (int i = 0; i < 8; ++i) {
            int r = br + i * 4;
            Bs[r][bc] = Bb[(size_t)(k0 + r) * ldb + bc];
        }
        __syncthreads();
        #pragma unroll
        for (int kk = 0; kk < 32; ++kk) {
            float a[4], b[4];
            #pragma unroll
            for (int i = 0; i < 4; ++i) a[i] = As[ty * 4 + i][kk];
            #pragma unroll
            for (int j = 0; j < 4; ++j) b[j] = Bs[kk][tx * 4 + j];
            #pragma unroll
            for (int i = 0; i < 4; ++i)
                #pragma unroll
                for (int j = 0; j < 4; ++j) acc[i][j] += a[i] * b[j];
        }
        __syncthreads();
    }
    #pragma unroll
    for (int i = 0; i < 4; ++i) {
        int gm = m0 + ty * 4 + i;
        if (gm < M) {
            float* Cp = C + (size_t)gm * D_ALL + c * 64 + tx * 4;
            #pragma unroll
            for (int j = 0; j < 4; ++j) Cp[j] = acc[i][j];
        }
    }
}

// ---------------- aggregate (+ optional LayerNorm epilogue) ----------------
// one block (256 threads) per node; thread t -> channel t/64, dim t%64

__global__ __launch_bounds__(256) void agg_kernel(
    const float* __restrict__ lin,
    const int* __restrict__ row_start, const int* __restrict__ csr_src,
    const float* __restrict__ csr_coef, const float* __restrict__ selfn,
    const float* __restrict__ bias, int biasChanStride,
    float* __restrict__ hout,
    float* __restrict__ out, const float* __restrict__ gamma, const float* __restrict__ beta,
    int lastFlag)
{
    int i = blockIdx.x;
    int t = threadIdx.x;
    int c = t >> 6, d = t & 63;
    int s = row_start[i], e = row_start[i + 1];
    float acc = 0.f;
    for (int j = s; j < e; ++j) {
        int sn = csr_src[j];
        float w = csr_coef[j];
        acc += w * lin[(size_t)sn * D_ALL + t];
    }
    float tv = acc + selfn[i] * lin[(size_t)i * D_ALL + t] + bias[c * biasChanStride + d];
    float h = (tv > 0.f) ? tv + tv : tv;   // relu(t) + t
    if (!lastFlag) {
        hout[(size_t)i * D_ALL + t] = h;
    } else {
        // 64-lane (one wave = one channel) LayerNorm over d
        float sum = h, sq = h * h;
        #pragma unroll
        for (int off = 32; off > 0; off >>= 1) {
            sum += __shfl_xor(sum, off, 64);
            sq  += __shfl_xor(sq, off, 64);
        }
        float mu = sum * (1.f / 64.f);
        float var = sq * (1.f / 64.f) - mu * mu;
        float r = rsqrtf(var + 1e-6f);
        out[(size_t)c * N_NODES * D_H + (size_t)i * D_H + d] = (h - mu) * r * gamma[d] + beta[d];
    }
}

// ---------------- launch ----------------

extern "C" void kernel_launch(void* const* d_in, const int* in_sizes, int n_in,
                              void* d_out, int out_size, void* d_ws, size_t ws_size,
                              hipStream_t stream) {
    const float* x     = (const float*)d_in[0];
    const int*   edge  = (const int*)d_in[1];
    const float* W0    = (const float*)d_in[3];
    const float* b0    = (const float*)d_in[4];
    const float* Wl    = (const float*)d_in[5];
    const float* bl    = (const float*)d_in[6];
    const float* gamma = (const float*)d_in[7];
    const float* beta  = (const float*)d_in[8];
    float* out = (float*)d_out;

    const int* e_src = edge;            // edge[0]
    const int* e_dst = edge + N_EDGES;  // edge[1]

    char* ws = (char*)d_ws;
    size_t off = 0;
    auto alloc = [&](size_t bytes) -> void* {
        void* p = ws + off;
        off = (off + bytes + 255) & ~(size_t)255;
        return p;
    };
    int*   deg_cnt   = (int*)  alloc(sizeof(int)   * N_NODES);
    int*   cursor    = (int*)  alloc(sizeof(int)   * N_NODES);
    int*   row_start = (int*)  alloc(sizeof(int)   * (N_NODES + 1));
    float* dinv      = (float*)alloc(sizeof(float) * N_NODES);
    float* selfn     = (float*)alloc(sizeof(float) * N_NODES);
    int*   csr_src   = (int*)  alloc(sizeof(int)   * N_EDGES);
    float* csr_coef  = (float*)alloc(sizeof(float) * N_EDGES);
    float* Wcat      = (float*)alloc(sizeof(float) * D_IN * D_ALL);
    float* lin       = (float*)alloc(sizeof(float) * (size_t)N_NODES * D_ALL);
    float* h         = (float*)alloc(sizeof(float) * (size_t)N_NODES * D_ALL);

    const int nb_n = (N_NODES + 255) / 256;
    const int nb_e = (N_EDGES + 255) / 256;

    init_deg_kernel<<<nb_n, 256, 0, stream>>>(deg_cnt, cursor, N_NODES);
    hist_kernel<<<nb_e, 256, 0, stream>>>(e_dst, deg_cnt, N_EDGES);
    dinv_kernel<<<nb_n, 256, 0, stream>>>(deg_cnt, dinv, selfn, N_NODES);
    scan_kernel<<<1, 1024, 0, stream>>>(deg_cnt, row_start, N_NODES);
    csr_build_kernel<<<nb_e, 256, 0, stream>>>(e_src, e_dst, row_start, cursor, dinv,
                                               csr_src, csr_coef, N_EDGES);
    pack_w_kernel<<<(D_IN * D_ALL) / 256, 256, 0, stream>>>(W0, Wcat);

    dim3 ggrid((N_NODES + 63) / 64, SZ_C);

    // layer 0: lin = x @ Wcat ; h = agg(lin)
    gemm_kernel<<<ggrid, 256, 0, stream>>>(x, D_IN, 0, Wcat, D_ALL, 64, lin, N_NODES, D_IN);
    agg_kernel<<<N_NODES, 256, 0, stream>>>(lin, row_start, csr_src, csr_coef, selfn,
                                            b0, 64, h, nullptr, nullptr, nullptr, 0);
    // layer 1: weights Wl[c][0]
    gemm_kernel<<<ggrid, 256, 0, stream>>>(h, D_ALL, 64, Wl, 64, 2 * 64 * 64, lin, N_NODES, 64);
    agg_kernel<<<N_NODES, 256, 0, stream>>>(lin, row_start, csr_src, csr_coef, selfn,
                                            bl, 2 * 64, h, nullptr, nullptr, nullptr, 0);
    // layer 2: weights Wl[c][1], fused LayerNorm epilogue -> d_out
    gemm_kernel<<<ggrid, 256, 0, stream>>>(h, D_ALL, 64, Wl + 64 * 64, 64, 2 * 64 * 64, lin, N_NODES, 64);
    agg_kernel<<<N_NODES, 256, 0, stream>>>(lin, row_start, csr_src, csr_coef, selfn,
                                            bl + 64, 2 * 64, nullptr, out, gamma, beta, 1);
}

// Round 2
// 478.007 us; speedup vs baseline: 1.8569x; 1.8569x over previous
//
#include <hip/hip_runtime.h>
#include <hip/hip_bf16.h>

#define N_NODES 50000
#define N_EDGES 800000
#define D_IN    128
#define D_H     64
#define SZ_C    4
#define D_ALL   (SZ_C * D_H)   // 256

__device__ __forceinline__ float bf2f(unsigned short u) {
    return __uint_as_float(((unsigned)u) << 16);
}
__device__ __forceinline__ unsigned short f2bf(float f) {
    unsigned u = __float_as_uint(f);
    unsigned r = (u + 0x7fffu + ((u >> 16) & 1u)) >> 16;   // round-to-nearest-even
    return (unsigned short)r;
}

// ---------------- setup kernels ----------------

__global__ void init_deg_kernel(int* __restrict__ deg_cnt, int* __restrict__ cursor, int n) {
    int i = blockIdx.x * blockDim.x + threadIdx.x;
    if (i < n) { deg_cnt[i] = 0; cursor[i] = 0; }
}

__global__ void hist_kernel(const int* __restrict__ dst, int* __restrict__ deg_cnt, int e) {
    int i = blockIdx.x * blockDim.x + threadIdx.x;
    if (i < e) atomicAdd(&deg_cnt[dst[i]], 1);
}

__global__ void dinv_kernel(const int* __restrict__ deg_cnt, float* __restrict__ dinv,
                            float* __restrict__ selfn, int n) {
    int i = blockIdx.x * blockDim.x + threadIdx.x;
    if (i < n) {
        float df = (float)deg_cnt[i] + 1.0f;
        float dv = rsqrtf(df);
        dinv[i] = dv;
        selfn[i] = dv * dv;
    }
}

// exclusive scan: row_start[0]=0, row_start[i+1]=sum cnt[0..i]; single block, shfl-based
__global__ void scan_kernel(const int* __restrict__ cnt, int* __restrict__ row_start, int n) {
    __shared__ int wsum[16];
    __shared__ int s_running;
    int t = threadIdx.x;
    int lane = t & 63, wv = t >> 6;
    if (t == 0) { s_running = 0; row_start[0] = 0; }
    __syncthreads();
    for (int base = 0; base < n; base += 1024) {
        int v = (base + t < n) ? cnt[base + t] : 0;
        int x = v;
        #pragma unroll
        for (int off = 1; off < 64; off <<= 1) {
            int y = __shfl_up(x, off, 64);
            if (lane >= off) x += y;
        }
        if (lane == 63) wsum[wv] = x;
        __syncthreads();
        if (wv == 0 && lane < 16) {
            int ws = wsum[lane];
            #pragma unroll
            for (int off = 1; off < 16; off <<= 1) {
                int y = __shfl_up(ws, off, 64);
                if (lane >= off) ws += y;
            }
            wsum[lane] = ws;  // inclusive wave prefix
        }
        __syncthreads();
        int wbase = (wv == 0) ? 0 : wsum[wv - 1];
        int incl = x + wbase + s_running;
        if (base + t < n) row_start[base + t + 1] = incl;
        __syncthreads();
        if (t == 1023) s_running = incl;
        __syncthreads();
    }
}

__global__ void csr_build_kernel(const int* __restrict__ src, const int* __restrict__ dst,
                                 const int* __restrict__ row_start, int* __restrict__ cursor,
                                 const float* __restrict__ dinv,
                                 int2* __restrict__ csr_ec, int e) {
    int i = blockIdx.x * blockDim.x + threadIdx.x;
    if (i < e) {
        int d = dst[i];
        int s = src[i];
        int pos = row_start[d] + atomicAdd(&cursor[d], 1);
        int2 rec;
        rec.x = s;
        rec.y = __float_as_int(dinv[s] * dinv[d]);
        csr_ec[pos] = rec;
    }
}

// pack W0 [4,128,64] -> Wcat [128,256] row-major
__global__ void pack_w_kernel(const float* __restrict__ W0, float* __restrict__ Wcat) {
    int tid = blockIdx.x * blockDim.x + threadIdx.x;  // 0..32767
    int k = tid >> 8;
    int r = tid & 255;
    int c = r >> 6;
    int d = r & 63;
    Wcat[tid] = W0[c * (D_IN * D_H) + k * D_H + d];
}

// ---------------- GEMM (fp32 in, bf16 out) ----------------
// C[m, c*64+d] = sum_k A[m*lda + aChanOff*c + k] * B[bChanStride*c + k*ldb + d]

__global__ __launch_bounds__(256) void gemm_kernel(
    const float* __restrict__ A, int lda, int aChanOff,
    const float* __restrict__ B, int ldb, int bChanStride,
    unsigned short* __restrict__ C, int M, int K)
{
    __shared__ float As[64][33];
    __shared__ float Bs[32][65];
    int c = blockIdx.y;
    int m0 = blockIdx.x * 64;
    const float* Ab = A + (size_t)aChanOff * c;
    const float* Bb = B + (size_t)bChanStride * c;
    int t = threadIdx.x;
    int tx = t & 15, ty = t >> 4;
    float acc[4][4] = {};
    for (int k0 = 0; k0 < K; k0 += 32) {
        int ar = t >> 5, akk = t & 31;
        #pragma unroll
        for (int i = 0; i < 8; ++i) {
            int r = ar + i * 8;
            int gm = m0 + r;
            As[r][akk] = (gm < M) ? Ab[(size_t)gm * lda + k0 + akk] : 0.f;
        }
        int br = t >> 6, bc = t & 63;
        #pragma unroll
        for (int i = 0; i < 8; ++i) {
            int r = br + i * 4;
            Bs[r][bc] = Bb[(size_t)(k0 + r) * ldb + bc];
        }
        __syncthreads();
        #pragma unroll
        for (int kk = 0; kk < 32; ++kk) {
            float a[4], b[4];
            #pragma unroll
            for (int i = 0; i < 4; ++i) a[i] = As[ty * 4 + i][kk];
            #pragma unroll
            for (int j = 0; j < 4; ++j) b[j] = Bs[kk][tx * 4 + j];
            #pragma unroll
            for (int i = 0; i < 4; ++i)
                #pragma unroll
                for (int j = 0; j < 4; ++j) acc[i][j] += a[i] * b[j];
        }
        __syncthreads();
    }
    #pragma unroll
    for (int i = 0; i < 4; ++i) {
        int gm = m0 + ty * 4 + i;
        if (gm < M) {
            ushort4 v;
            v.x = f2bf(acc[i][0]); v.y = f2bf(acc[i][1]);
            v.z = f2bf(acc[i][2]); v.w = f2bf(acc[i][3]);
            *(ushort4*)(C + (size_t)gm * D_ALL + c * 64 + tx * 4) = v;
        }
    }
}

// ---------------- aggregate (+ optional LayerNorm epilogue) ----------------
// one wave per node (4 nodes / 256-thread block); lane owns dims 4*lane..4*lane+3

__global__ __launch_bounds__(256) void agg_kernel(
    const unsigned short* __restrict__ lin,  // bf16 [N,256]
    const int* __restrict__ row_start,
    const int2* __restrict__ csr_ec,
    const float* __restrict__ selfn,
    const float* __restrict__ bias, int biasChanStride,
    float* __restrict__ hout,                // fp32 [N,256] (layers 0,1)
    float* __restrict__ out, const float* __restrict__ gamma, const float* __restrict__ beta,
    int lastFlag)
{
    int w = threadIdx.x >> 6;
    int lane = threadIdx.x & 63;
    int i = blockIdx.x * 4 + w;

    int s = row_start[i], e = row_start[i + 1];
    float a0 = 0.f, a1 = 0.f, a2 = 0.f, a3 = 0.f;
    const unsigned short* lb = lin + (size_t)lane * 4;

    int j = s;
    for (; j + 3 < e; j += 4) {
        int2 e0 = csr_ec[j], e1 = csr_ec[j + 1], e2 = csr_ec[j + 2], e3 = csr_ec[j + 3];
        ushort4 u0 = *(const ushort4*)(lb + (size_t)e0.x * D_ALL);
        ushort4 u1 = *(const ushort4*)(lb + (size_t)e1.x * D_ALL);
        ushort4 u2 = *(const ushort4*)(lb + (size_t)e2.x * D_ALL);
        ushort4 u3 = *(const ushort4*)(lb + (size_t)e3.x * D_ALL);
        float c0 = __int_as_float(e0.y), c1 = __int_as_float(e1.y);
        float c2 = __int_as_float(e2.y), c3 = __int_as_float(e3.y);
        a0 += c0 * bf2f(u0.x) + c1 * bf2f(u1.x) + c2 * bf2f(u2.x) + c3 * bf2f(u3.x);
        a1 += c0 * bf2f(u0.y) + c1 * bf2f(u1.y) + c2 * bf2f(u2.y) + c3 * bf2f(u3.y);
        a2 += c0 * bf2f(u0.z) + c1 * bf2f(u1.z) + c2 * bf2f(u2.z) + c3 * bf2f(u3.z);
        a3 += c0 * bf2f(u0.w) + c1 * bf2f(u1.w) + c2 * bf2f(u2.w) + c3 * bf2f(u3.w);
    }
    for (; j < e; ++j) {
        int2 ec = csr_ec[j];
        ushort4 u = *(const ushort4*)(lb + (size_t)ec.x * D_ALL);
        float cf = __int_as_float(ec.y);
        a0 += cf * bf2f(u.x); a1 += cf * bf2f(u.y);
        a2 += cf * bf2f(u.z); a3 += cf * bf2f(u.w);
    }

    // self-loop + bias
    ushort4 us = *(const ushort4*)(lb + (size_t)i * D_ALL);
    float sn = selfn[i];
    int c = lane >> 4;
    int dbase = (lane & 15) * 4;
    const float* bp = bias + c * biasChanStride + dbase;
    float t0 = a0 + sn * bf2f(us.x) + bp[0];
    float t1 = a1 + sn * bf2f(us.y) + bp[1];
    float t2 = a2 + sn * bf2f(us.z) + bp[2];
    float t3 = a3 + sn * bf2f(us.w) + bp[3];
    float h0 = (t0 > 0.f) ? t0 + t0 : t0;
    float h1 = (t1 > 0.f) ? t1 + t1 : t1;
    float h2 = (t2 > 0.f) ? t2 + t2 : t2;
    float h3 = (t3 > 0.f) ? t3 + t3 : t3;

    if (!lastFlag) {
        float4 v = make_float4(h0, h1, h2, h3);
        *(float4*)(hout + (size_t)i * D_ALL + lane * 4) = v;
    } else {
        // LayerNorm over each channel's 64 dims = 16-lane group x 4 dims
        float sum = h0 + h1 + h2 + h3;
        float sq = h0 * h0 + h1 * h1 + h2 * h2 + h3 * h3;
        #pragma unroll
        for (int off = 1; off < 16; off <<= 1) {
            sum += __shfl_xor(sum, off, 64);
            sq  += __shfl_xor(sq, off, 64);
        }
        float mu = sum * (1.f / 64.f);
        float var = sq * (1.f / 64.f) - mu * mu;
        float r = rsqrtf(var + 1e-6f);
        const float* gp = gamma + dbase;
        const float* bp2 = beta + dbase;
        float4 o;
        o.x = (h0 - mu) * r * gp[0] + bp2[0];
        o.y = (h1 - mu) * r * gp[1] + bp2[1];
        o.z = (h2 - mu) * r * gp[2] + bp2[2];
        o.w = (h3 - mu) * r * gp[3] + bp2[3];
        *(float4*)(out + (size_t)c * N_NODES * D_H + (size_t)i * D_H + dbase) = o;
    }
}

// ---------------- launch ----------------

extern "C" void kernel_launch(void* const* d_in, const int* in_sizes, int n_in,
                              void* d_out, int out_size, void* d_ws, size_t ws_size,
                              hipStream_t stream) {
    const float* x     = (const float*)d_in[0];
    const int*   edge  = (const int*)d_in[1];
    const float* W0    = (const float*)d_in[3];
    const float* b0    = (const float*)d_in[4];
    const float* Wl    = (const float*)d_in[5];
    const float* bl    = (const float*)d_in[6];
    const float* gamma = (const float*)d_in[7];
    const float* beta  = (const float*)d_in[8];
    float* out = (float*)d_out;

    const int* e_src = edge;            // edge[0]
    const int* e_dst = edge + N_EDGES;  // edge[1]

    char* ws = (char*)d_ws;
    size_t off = 0;
    auto alloc = [&](size_t bytes) -> void* {
        void* p = ws + off;
        off = (off + bytes + 255) & ~(size_t)255;
        return p;
    };
    int*   deg_cnt   = (int*)  alloc(sizeof(int)   * N_NODES);
    int*   cursor    = (int*)  alloc(sizeof(int)   * N_NODES);
    int*   row_start = (int*)  alloc(sizeof(int)   * (N_NODES + 1));
    float* dinv      = (float*)alloc(sizeof(float) * N_NODES);
    float* selfn     = (float*)alloc(sizeof(float) * N_NODES);
    int2*  csr_ec    = (int2*) alloc(sizeof(int2)  * N_EDGES);
    float* Wcat      = (float*)alloc(sizeof(float) * D_IN * D_ALL);
    unsigned short* lin = (unsigned short*)alloc(sizeof(unsigned short) * (size_t)N_NODES * D_ALL);
    float* h         = (float*)alloc(sizeof(float) * (size_t)N_NODES * D_ALL);

    const int nb_n = (N_NODES + 255) / 256;
    const int nb_e = (N_EDGES + 255) / 256;

    init_deg_kernel<<<nb_n, 256, 0, stream>>>(deg_cnt, cursor, N_NODES);
    hist_kernel<<<nb_e, 256, 0, stream>>>(e_dst, deg_cnt, N_EDGES);
    dinv_kernel<<<nb_n, 256, 0, stream>>>(deg_cnt, dinv, selfn, N_NODES);
    scan_kernel<<<1, 1024, 0, stream>>>(deg_cnt, row_start, N_NODES);
    csr_build_kernel<<<nb_e, 256, 0, stream>>>(e_src, e_dst, row_start, cursor, dinv,
                                               csr_ec, N_EDGES);
    pack_w_kernel<<<(D_IN * D_ALL) / 256, 256, 0, stream>>>(W0, Wcat);

    dim3 ggrid((N_NODES + 63) / 64, SZ_C);
    const int agg_grid = N_NODES / 4;  // 12500, exact

    // layer 0
    gemm_kernel<<<ggrid, 256, 0, stream>>>(x, D_IN, 0, Wcat, D_ALL, 64, lin, N_NODES, D_IN);
    agg_kernel<<<agg_grid, 256, 0, stream>>>(lin, row_start, csr_ec, selfn,
                                             b0, 64, h, nullptr, nullptr, nullptr, 0);
    // layer 1
    gemm_kernel<<<ggrid, 256, 0, stream>>>(h, D_ALL, 64, Wl, 64, 2 * 64 * 64, lin, N_NODES, 64);
    agg_kernel<<<agg_grid, 256, 0, stream>>>(lin, row_start, csr_ec, selfn,
                                             bl, 2 * 64, h, nullptr, nullptr, nullptr, 0);
    // layer 2 + fused LayerNorm -> d_out
    gemm_kernel<<<ggrid, 256, 0, stream>>>(h, D_ALL, 64, Wl + 64 * 64, 64, 2 * 64 * 64, lin, N_NODES, 64);
    agg_kernel<<<agg_grid, 256, 0, stream>>>(lin, row_start, csr_ec, selfn,
                                             bl + 64, 2 * 64, nullptr, out, gamma, beta, 1);
}

// Round 3
// 373.971 us; speedup vs baseline: 2.3735x; 1.2782x over previous
//
#include <hip/hip_runtime.h>
#include <hip/hip_bf16.h>

#define N_NODES 50000
#define N_EDGES 800000
#define D_IN    128
#define D_H     64
#define SZ_C    4
#define D_ALL   (SZ_C * D_H)   // 256

typedef __bf16 bf16x8 __attribute__((ext_vector_type(8)));
typedef float  f32x4  __attribute__((ext_vector_type(4)));

__device__ __forceinline__ float bf2f(unsigned short u) {
    return __uint_as_float(((unsigned)u) << 16);
}
__device__ __forceinline__ unsigned short f2bf(float f) {
    unsigned u = __float_as_uint(f);
    unsigned r = (u + 0x7fffu + ((u >> 16) & 1u)) >> 16;   // round-to-nearest-even
    return (unsigned short)r;
}

// ---------------- setup kernels ----------------

__global__ void init_deg_kernel(int* __restrict__ deg_cnt, int* __restrict__ cursor, int n) {
    int i = blockIdx.x * blockDim.x + threadIdx.x;
    if (i < n) { deg_cnt[i] = 0; cursor[i] = 0; }
}

__global__ void hist_kernel(const int* __restrict__ dst, int* __restrict__ deg_cnt, int e) {
    int i = blockIdx.x * blockDim.x + threadIdx.x;
    if (i < e) atomicAdd(&deg_cnt[dst[i]], 1);
}

__global__ void dinv_kernel(const int* __restrict__ deg_cnt, float* __restrict__ dinv,
                            float* __restrict__ selfn, int n) {
    int i = blockIdx.x * blockDim.x + threadIdx.x;
    if (i < n) {
        float df = (float)deg_cnt[i] + 1.0f;
        float dv = rsqrtf(df);
        dinv[i] = dv;
        selfn[i] = dv * dv;
    }
}

// exclusive scan: row_start[0]=0, row_start[i+1]=sum cnt[0..i]; single block, shfl-based
__global__ void scan_kernel(const int* __restrict__ cnt, int* __restrict__ row_start, int n) {
    __shared__ int wsum[16];
    __shared__ int s_running;
    int t = threadIdx.x;
    int lane = t & 63, wv = t >> 6;
    if (t == 0) { s_running = 0; row_start[0] = 0; }
    __syncthreads();
    for (int base = 0; base < n; base += 1024) {
        int v = (base + t < n) ? cnt[base + t] : 0;
        int x = v;
        #pragma unroll
        for (int off = 1; off < 64; off <<= 1) {
            int y = __shfl_up(x, off, 64);
            if (lane >= off) x += y;
        }
        if (lane == 63) wsum[wv] = x;
        __syncthreads();
        if (wv == 0 && lane < 16) {
            int ws = wsum[lane];
            #pragma unroll
            for (int off = 1; off < 16; off <<= 1) {
                int y = __shfl_up(ws, off, 64);
                if (lane >= off) ws += y;
            }
            wsum[lane] = ws;  // inclusive wave prefix
        }
        __syncthreads();
        int wbase = (wv == 0) ? 0 : wsum[wv - 1];
        int incl = x + wbase + s_running;
        if (base + t < n) row_start[base + t + 1] = incl;
        __syncthreads();
        if (t == 1023) s_running = incl;
        __syncthreads();
    }
}

__global__ void csr_build_kernel(const int* __restrict__ src, const int* __restrict__ dst,
                                 const int* __restrict__ row_start, int* __restrict__ cursor,
                                 const float* __restrict__ dinv,
                                 int2* __restrict__ csr_ec, int e) {
    int i = blockIdx.x * blockDim.x + threadIdx.x;
    if (i < e) {
        int d = dst[i];
        int s = src[i];
        int pos = row_start[d] + atomicAdd(&cursor[d], 1);
        int2 rec;
        rec.x = s;
        rec.y = __float_as_int(dinv[s] * dinv[d]);
        csr_ec[pos] = rec;
    }
}

// fp32 -> bf16 elementwise (n multiple of 4)
__global__ void f2bf_kernel(const float* __restrict__ in, unsigned short* __restrict__ out, int n4) {
    int i = blockIdx.x * blockDim.x + threadIdx.x;
    if (i < n4) {
        float4 v = ((const float4*)in)[i];
        ushort4 o;
        o.x = f2bf(v.x); o.y = f2bf(v.y); o.z = f2bf(v.z); o.w = f2bf(v.w);
        ((ushort4*)out)[i] = o;
    }
}

// Pack weight W [4ch][K][64] (fp32, channel stride chanStride) into MFMA B-frag layout:
// P[((c*ksteps + ks)*4 + n)*512 + lane*8 + j] = bf16(W[c][ks*32 + (lane>>4)*8 + j][n*16 + (lane&15)])
__global__ void pack_b_kernel(const float* __restrict__ W, int chanStride, int ksteps,
                              unsigned short* __restrict__ P, int total) {
    int tid = blockIdx.x * blockDim.x + threadIdx.x;
    if (tid >= total) return;
    int j = tid & 7;
    int lane = (tid >> 3) & 63;
    int n = (tid >> 9) & 3;
    int cks = tid >> 11;
    int ks = cks % ksteps;
    int c = cks / ksteps;
    int k = ks * 32 + (lane >> 4) * 8 + j;
    int d = n * 16 + (lane & 15);
    P[tid] = f2bf(W[(size_t)c * chanStride + (size_t)k * 64 + d]);
}

// ---------------- MFMA GEMM (bf16 in, bf16 out, fp32 acc) ----------------
// C[m, c*64 + n*16 + col] ; A [M, lda] bf16 with per-channel col offset aChanOff*c.
// grid: (ceil(M/64), 4), block 256 = 4 waves; wave w -> rows m0+16w..+15, all 64 cols.

__global__ __launch_bounds__(256) void mfma_gemm_kernel(
    const unsigned short* __restrict__ A, int lda, int aChanOff,
    const unsigned short* __restrict__ Bpack, int ksteps,
    unsigned short* __restrict__ C, int M)
{
    int c = blockIdx.y;
    int m0 = blockIdx.x * 64;
    int w = threadIdx.x >> 6, lane = threadIdx.x & 63;
    int arow = m0 + w * 16 + (lane & 15);
    int arow_c = (arow < M) ? arow : (M - 1);   // clamp: bad rows only feed guarded stores
    const unsigned short* Ap = A + (size_t)arow_c * lda + aChanOff * c + (lane >> 4) * 8;
    const unsigned short* Bp = Bpack + ((size_t)c * ksteps * 4) * 512 + (size_t)(lane & 63) * 8;
    f32x4 acc[4] = {};
    for (int ks = 0; ks < ksteps; ++ks) {
        bf16x8 af = *(const bf16x8*)(Ap + ks * 32);
        const unsigned short* b = Bp + (size_t)ks * 2048;
        #pragma unroll
        for (int n = 0; n < 4; ++n) {
            bf16x8 bfr = *(const bf16x8*)(b + n * 512);
            acc[n] = __builtin_amdgcn_mfma_f32_16x16x32_bf16(af, bfr, acc[n], 0, 0, 0);
        }
    }
    int colbase = c * 64 + (lane & 15);
    int rbase = m0 + w * 16 + (lane >> 4) * 4;
    #pragma unroll
    for (int n = 0; n < 4; ++n) {
        #pragma unroll
        for (int r = 0; r < 4; ++r) {
            int rr = rbase + r;
            if (rr < M) C[(size_t)rr * D_ALL + colbase + n * 16] = f2bf(acc[n][r]);
        }
    }
}

// ---------------- aggregate (+ optional LayerNorm epilogue) ----------------
// one wave per node (4 nodes / 256-thread block); lane owns dims 4*lane..4*lane+3

__global__ __launch_bounds__(256) void agg_kernel(
    const unsigned short* __restrict__ lin,  // bf16 [N,256]
    const int* __restrict__ row_start,
    const int2* __restrict__ csr_ec,
    const float* __restrict__ selfn,
    const float* __restrict__ bias, int biasChanStride,
    unsigned short* __restrict__ hout,       // bf16 [N,256] (layers 0,1)
    float* __restrict__ out, const float* __restrict__ gamma, const float* __restrict__ beta,
    int lastFlag)
{
    int w = threadIdx.x >> 6;
    int lane = threadIdx.x & 63;
    int i = blockIdx.x * 4 + w;

    int s = row_start[i], e = row_start[i + 1];
    float a0 = 0.f, a1 = 0.f, a2 = 0.f, a3 = 0.f;
    const unsigned short* lb = lin + (size_t)lane * 4;

    int j = s;
    for (; j + 3 < e; j += 4) {
        int2 e0 = csr_ec[j], e1 = csr_ec[j + 1], e2 = csr_ec[j + 2], e3 = csr_ec[j + 3];
        ushort4 u0 = *(const ushort4*)(lb + (size_t)e0.x * D_ALL);
        ushort4 u1 = *(const ushort4*)(lb + (size_t)e1.x * D_ALL);
        ushort4 u2 = *(const ushort4*)(lb + (size_t)e2.x * D_ALL);
        ushort4 u3 = *(const ushort4*)(lb + (size_t)e3.x * D_ALL);
        float c0 = __int_as_float(e0.y), c1 = __int_as_float(e1.y);
        float c2 = __int_as_float(e2.y), c3 = __int_as_float(e3.y);
        a0 += c0 * bf2f(u0.x) + c1 * bf2f(u1.x) + c2 * bf2f(u2.x) + c3 * bf2f(u3.x);
        a1 += c0 * bf2f(u0.y) + c1 * bf2f(u1.y) + c2 * bf2f(u2.y) + c3 * bf2f(u3.y);
        a2 += c0 * bf2f(u0.z) + c1 * bf2f(u1.z) + c2 * bf2f(u2.z) + c3 * bf2f(u3.z);
        a3 += c0 * bf2f(u0.w) + c1 * bf2f(u1.w) + c2 * bf2f(u2.w) + c3 * bf2f(u3.w);
    }
    for (; j < e; ++j) {
        int2 ec = csr_ec[j];
        ushort4 u = *(const ushort4*)(lb + (size_t)ec.x * D_ALL);
        float cf = __int_as_float(ec.y);
        a0 += cf * bf2f(u.x); a1 += cf * bf2f(u.y);
        a2 += cf * bf2f(u.z); a3 += cf * bf2f(u.w);
    }

    // self-loop + bias
    ushort4 us = *(const ushort4*)(lb + (size_t)i * D_ALL);
    float sn = selfn[i];
    int c = lane >> 4;
    int dbase = (lane & 15) * 4;
    const float* bp = bias + c * biasChanStride + dbase;
    float t0 = a0 + sn * bf2f(us.x) + bp[0];
    float t1 = a1 + sn * bf2f(us.y) + bp[1];
    float t2 = a2 + sn * bf2f(us.z) + bp[2];
    float t3 = a3 + sn * bf2f(us.w) + bp[3];
    float h0 = (t0 > 0.f) ? t0 + t0 : t0;
    float h1 = (t1 > 0.f) ? t1 + t1 : t1;
    float h2 = (t2 > 0.f) ? t2 + t2 : t2;
    float h3 = (t3 > 0.f) ? t3 + t3 : t3;

    if (!lastFlag) {
        ushort4 v;
        v.x = f2bf(h0); v.y = f2bf(h1); v.z = f2bf(h2); v.w = f2bf(h3);
        *(ushort4*)(hout + (size_t)i * D_ALL + lane * 4) = v;
    } else {
        // LayerNorm over each channel's 64 dims = 16-lane group x 4 dims
        float sum = h0 + h1 + h2 + h3;
        float sq = h0 * h0 + h1 * h1 + h2 * h2 + h3 * h3;
        #pragma unroll
        for (int off = 1; off < 16; off <<= 1) {
            sum += __shfl_xor(sum, off, 64);
            sq  += __shfl_xor(sq, off, 64);
        }
        float mu = sum * (1.f / 64.f);
        float var = sq * (1.f / 64.f) - mu * mu;
        float r = rsqrtf(var + 1e-6f);
        const float* gp = gamma + dbase;
        const float* bp2 = beta + dbase;
        float4 o;
        o.x = (h0 - mu) * r * gp[0] + bp2[0];
        o.y = (h1 - mu) * r * gp[1] + bp2[1];
        o.z = (h2 - mu) * r * gp[2] + bp2[2];
        o.w = (h3 - mu) * r * gp[3] + bp2[3];
        *(float4*)(out + (size_t)c * N_NODES * D_H + (size_t)i * D_H + dbase) = o;
    }
}

// ---------------- launch ----------------

extern "C" void kernel_launch(void* const* d_in, const int* in_sizes, int n_in,
                              void* d_out, int out_size, void* d_ws, size_t ws_size,
                              hipStream_t stream) {
    const float* x     = (const float*)d_in[0];
    const int*   edge  = (const int*)d_in[1];
    const float* W0    = (const float*)d_in[3];
    const float* b0    = (const float*)d_in[4];
    const float* Wl    = (const float*)d_in[5];
    const float* bl    = (const float*)d_in[6];
    const float* gamma = (const float*)d_in[7];
    const float* beta  = (const float*)d_in[8];
    float* out = (float*)d_out;

    const int* e_src = edge;            // edge[0]
    const int* e_dst = edge + N_EDGES;  // edge[1]

    char* ws = (char*)d_ws;
    size_t off = 0;
    auto alloc = [&](size_t bytes) -> void* {
        void* p = ws + off;
        off = (off + bytes + 255) & ~(size_t)255;
        return p;
    };
    int*   deg_cnt   = (int*)  alloc(sizeof(int)   * N_NODES);
    int*   cursor    = (int*)  alloc(sizeof(int)   * N_NODES);
    int*   row_start = (int*)  alloc(sizeof(int)   * (N_NODES + 1));
    float* dinv      = (float*)alloc(sizeof(float) * N_NODES);
    float* selfn     = (float*)alloc(sizeof(float) * N_NODES);
    int2*  csr_ec    = (int2*) alloc(sizeof(int2)  * N_EDGES);
    unsigned short* x_bf  = (unsigned short*)alloc(sizeof(unsigned short) * (size_t)N_NODES * D_IN);
    unsigned short* W0p   = (unsigned short*)alloc(sizeof(unsigned short) * SZ_C * 4 * 4 * 512);
    unsigned short* Wl0p  = (unsigned short*)alloc(sizeof(unsigned short) * SZ_C * 2 * 4 * 512);
    unsigned short* Wl1p  = (unsigned short*)alloc(sizeof(unsigned short) * SZ_C * 2 * 4 * 512);
    unsigned short* lin   = (unsigned short*)alloc(sizeof(unsigned short) * (size_t)N_NODES * D_ALL);
    unsigned short* h_bf  = (unsigned short*)alloc(sizeof(unsigned short) * (size_t)N_NODES * D_ALL);

    const int nb_n = (N_NODES + 255) / 256;
    const int nb_e = (N_EDGES + 255) / 256;

    init_deg_kernel<<<nb_n, 256, 0, stream>>>(deg_cnt, cursor, N_NODES);
    hist_kernel<<<nb_e, 256, 0, stream>>>(e_dst, deg_cnt, N_EDGES);
    dinv_kernel<<<nb_n, 256, 0, stream>>>(deg_cnt, dinv, selfn, N_NODES);
    scan_kernel<<<1, 1024, 0, stream>>>(deg_cnt, row_start, N_NODES);
    csr_build_kernel<<<nb_e, 256, 0, stream>>>(e_src, e_dst, row_start, cursor, dinv,
                                               csr_ec, N_EDGES);
    // weight packing + x conversion
    pack_b_kernel<<<(SZ_C * 4 * 4 * 512 + 255) / 256, 256, 0, stream>>>(
        W0, D_IN * D_H, 4, W0p, SZ_C * 4 * 4 * 512);
    pack_b_kernel<<<(SZ_C * 2 * 4 * 512 + 255) / 256, 256, 0, stream>>>(
        Wl, 2 * D_H * D_H, 2, Wl0p, SZ_C * 2 * 4 * 512);
    pack_b_kernel<<<(SZ_C * 2 * 4 * 512 + 255) / 256, 256, 0, stream>>>(
        Wl + D_H * D_H, 2 * D_H * D_H, 2, Wl1p, SZ_C * 2 * 4 * 512);
    f2bf_kernel<<<((N_NODES * D_IN / 4) + 255) / 256, 256, 0, stream>>>(
        x, x_bf, N_NODES * D_IN / 4);

    dim3 ggrid((N_NODES + 63) / 64, SZ_C);
    const int agg_grid = N_NODES / 4;  // 12500, exact

    // layer 0
    mfma_gemm_kernel<<<ggrid, 256, 0, stream>>>(x_bf, D_IN, 0, W0p, 4, lin, N_NODES);
    agg_kernel<<<agg_grid, 256, 0, stream>>>(lin, row_start, csr_ec, selfn,
                                             b0, 64, h_bf, nullptr, nullptr, nullptr, 0);
    // layer 1
    mfma_gemm_kernel<<<ggrid, 256, 0, stream>>>(h_bf, D_ALL, 64, Wl0p, 2, lin, N_NODES);
    agg_kernel<<<agg_grid, 256, 0, stream>>>(lin, row_start, csr_ec, selfn,
                                             bl, 2 * 64, h_bf, nullptr, nullptr, nullptr, 0);
    // layer 2 + fused LayerNorm -> d_out
    mfma_gemm_kernel<<<ggrid, 256, 0, stream>>>(h_bf, D_ALL, 64, Wl1p, 2, lin, N_NODES);
    agg_kernel<<<agg_grid, 256, 0, stream>>>(lin, row_start, csr_ec, selfn,
                                             bl + 64, 2 * 64, nullptr, out, gamma, beta, 1);
}

// Round 4
// 356.561 us; speedup vs baseline: 2.4894x; 1.0488x over previous
//
#include <hip/hip_runtime.h>
#include <hip/hip_bf16.h>

#define N_NODES 50000
#define N_EDGES 800000
#define D_IN    128
#define D_H     64
#define SZ_C    4
#define D_ALL   (SZ_C * D_H)   // 256

typedef __bf16 bf16x8 __attribute__((ext_vector_type(8)));
typedef float  f32x4  __attribute__((ext_vector_type(4)));
typedef unsigned short us8 __attribute__((ext_vector_type(8)));

__device__ __forceinline__ float bf2f(unsigned short u) {
    return __uint_as_float(((unsigned)u) << 16);
}
__device__ __forceinline__ unsigned short f2bf(float f) {
    unsigned u = __float_as_uint(f);
    unsigned r = (u + 0x7fffu + ((u >> 16) & 1u)) >> 16;   // round-to-nearest-even
    return (unsigned short)r;
}

// ---------------- setup kernels ----------------

// deg starts at 1: reserves the self-loop slot in each CSR row AND matches
// reference deg = in_deg + 1.
__global__ void init_deg_kernel(int* __restrict__ deg_cnt, int* __restrict__ cursor, int n) {
    int i = blockIdx.x * blockDim.x + threadIdx.x;
    if (i < n) { deg_cnt[i] = 1; cursor[i] = 0; }
}

__global__ void hist_kernel(const int* __restrict__ dst, int* __restrict__ deg_cnt, int e) {
    int i = blockIdx.x * blockDim.x + threadIdx.x;
    if (i < e) atomicAdd(&deg_cnt[dst[i]], 1);
}

__global__ void dinv_kernel(const int* __restrict__ deg_cnt, float* __restrict__ dinv, int n) {
    int i = blockIdx.x * blockDim.x + threadIdx.x;
    if (i < n) dinv[i] = rsqrtf((float)deg_cnt[i]);
}

// exclusive scan: row_start[0]=0, row_start[i+1]=sum cnt[0..i]; single block, shfl-based
__global__ void scan_kernel(const int* __restrict__ cnt, int* __restrict__ row_start, int n) {
    __shared__ int wsum[16];
    __shared__ int s_running;
    int t = threadIdx.x;
    int lane = t & 63, wv = t >> 6;
    if (t == 0) { s_running = 0; row_start[0] = 0; }
    __syncthreads();
    for (int base = 0; base < n; base += 1024) {
        int v = (base + t < n) ? cnt[base + t] : 0;
        int x = v;
        #pragma unroll
        for (int off = 1; off < 64; off <<= 1) {
            int y = __shfl_up(x, off, 64);
            if (lane >= off) x += y;
        }
        if (lane == 63) wsum[wv] = x;
        __syncthreads();
        if (wv == 0 && lane < 16) {
            int ws = wsum[lane];
            #pragma unroll
            for (int off = 1; off < 16; off <<= 1) {
                int y = __shfl_up(ws, off, 64);
                if (lane >= off) ws += y;
            }
            wsum[lane] = ws;  // inclusive wave prefix
        }
        __syncthreads();
        int wbase = (wv == 0) ? 0 : wsum[wv - 1];
        int incl = x + wbase + s_running;
        if (base + t < n) row_start[base + t + 1] = incl;
        __syncthreads();
        if (t == 1023) s_running = incl;
        __syncthreads();
    }
}

__global__ void csr_build_kernel(const int* __restrict__ src, const int* __restrict__ dst,
                                 const int* __restrict__ row_start, int* __restrict__ cursor,
                                 const float* __restrict__ dinv,
                                 int2* __restrict__ csr_ec, int e) {
    int i = blockIdx.x * blockDim.x + threadIdx.x;
    if (i < e) {
        int d = dst[i];
        int s = src[i];
        int pos = row_start[d] + atomicAdd(&cursor[d], 1);
        int2 rec;
        rec.x = s;
        rec.y = __float_as_int(dinv[s] * dinv[d]);
        csr_ec[pos] = rec;
    }
}

// self edge in the last (reserved) slot of each row: coef = dinv^2
__global__ void self_edge_kernel(const int* __restrict__ row_start, const float* __restrict__ dinv,
                                 int2* __restrict__ csr_ec, int n) {
    int i = blockIdx.x * blockDim.x + threadIdx.x;
    if (i < n) {
        float dv = dinv[i];
        int2 rec;
        rec.x = i;
        rec.y = __float_as_int(dv * dv);
        csr_ec[row_start[i + 1] - 1] = rec;
    }
}

// fp32 -> bf16 elementwise (n multiple of 4)
__global__ void f2bf_kernel(const float* __restrict__ in, unsigned short* __restrict__ out, int n4) {
    int i = blockIdx.x * blockDim.x + threadIdx.x;
    if (i < n4) {
        float4 v = ((const float4*)in)[i];
        ushort4 o;
        o.x = f2bf(v.x); o.y = f2bf(v.y); o.z = f2bf(v.z); o.w = f2bf(v.w);
        ((ushort4*)out)[i] = o;
    }
}

// Pack weight W [4ch][K][64] (fp32, channel stride chanStride) into MFMA B-frag layout:
// P[((c*ksteps + ks)*4 + n)*512 + lane*8 + j] = bf16(W[c][ks*32 + (lane>>4)*8 + j][n*16 + (lane&15)])
__global__ void pack_b_kernel(const float* __restrict__ W, int chanStride, int ksteps,
                              unsigned short* __restrict__ P, int total) {
    int tid = blockIdx.x * blockDim.x + threadIdx.x;
    if (tid >= total) return;
    int j = tid & 7;
    int lane = (tid >> 3) & 63;
    int n = (tid >> 9) & 3;
    int cks = tid >> 11;
    int ks = cks % ksteps;
    int c = cks / ksteps;
    int k = ks * 32 + (lane >> 4) * 8 + j;
    int d = n * 16 + (lane & 15);
    P[tid] = f2bf(W[(size_t)c * chanStride + (size_t)k * 64 + d]);
}

// ---------------- aggregation: z[i] = sum_j coef_j * h[src_j] (self edge included) ----
// one wave per node; lane = (group g, sublane sl); each lane loads 16 B (8 bf16 dims),
// group g handles edge j0+g -> D=256: 2 edges/instr, D=128: 4 edges/instr; unroll x2.

template<int D>
__global__ __launch_bounds__(256) void agg_kernel(
    const unsigned short* __restrict__ h,   // bf16 [N, D]
    const int* __restrict__ row_start,
    const int2* __restrict__ csr_ec,
    unsigned short* __restrict__ z)         // bf16 [N, D]
{
    constexpr int LPR = D / 8;      // lanes per row (16 or 32)
    constexpr int G   = 64 / LPR;   // edges per wave-instruction (4 or 2)
    int w = threadIdx.x >> 6;
    int lane = threadIdx.x & 63;
    int i = blockIdx.x * 4 + w;
    int g = lane / LPR;
    int sl = lane % LPR;
    int s = row_start[i], e = row_start[i + 1];
    float acc[8] = {};
    const unsigned short* hb = h + sl * 8;
    for (int j0 = s; j0 < e; j0 += 2 * G) {
        int ja = j0 + g, jb = j0 + G + g;
        int2 ea = (ja < e) ? csr_ec[ja] : make_int2(0, 0);
        int2 eb = (jb < e) ? csr_ec[jb] : make_int2(0, 0);
        us8 ua = *(const us8*)(hb + (size_t)ea.x * D);
        us8 ub = *(const us8*)(hb + (size_t)eb.x * D);
        float ca = __int_as_float(ea.y), cb = __int_as_float(eb.y);
        #pragma unroll
        for (int q = 0; q < 8; ++q)
            acc[q] += ca * bf2f(ua[q]) + cb * bf2f(ub[q]);
    }
    // butterfly-combine across edge groups
    #pragma unroll
    for (int off = LPR; off < 64; off <<= 1)
        #pragma unroll
        for (int q = 0; q < 8; ++q)
            acc[q] += __shfl_xor(acc[q], off, 64);
    if (g == 0) {
        us8 o;
        #pragma unroll
        for (int q = 0; q < 8; ++q) o[q] = f2bf(acc[q]);
        *(us8*)(z + (size_t)i * D + sl * 8) = o;
    }
}

// ---------------- MFMA GEMM + fused epilogue ----------------
// h' = relu(z@W + b) + (z@W + b); EPI=0: write bf16 h'; EPI=1: LayerNorm -> fp32 out
// grid: (ceil(M/64), 4 channels), block 256 = 4 waves; wave w -> rows m0+16w..+15.

template<int EPI>
__global__ __launch_bounds__(256) void mfma_gemm_kernel(
    const unsigned short* __restrict__ A, int lda, int aChanOff,
    const unsigned short* __restrict__ Bpack, int ksteps,
    const float* __restrict__ bias, int biasChanStride,
    unsigned short* __restrict__ Cbf,
    float* __restrict__ outF, const float* __restrict__ gamma, const float* __restrict__ beta,
    int M)
{
    int c = blockIdx.y;
    int m0 = blockIdx.x * 64;
    int w = threadIdx.x >> 6, lane = threadIdx.x & 63;
    int arow = m0 + w * 16 + (lane & 15);
    int arow_c = (arow < M) ? arow : (M - 1);   // clamp: bad rows only feed guarded stores
    const unsigned short* Ap = A + (size_t)arow_c * lda + aChanOff * c + (lane >> 4) * 8;
    const unsigned short* Bp = Bpack + ((size_t)c * ksteps * 4) * 512 + (size_t)lane * 8;
    f32x4 acc[4] = {};
    for (int ks = 0; ks < ksteps; ++ks) {
        bf16x8 af = *(const bf16x8*)(Ap + ks * 32);
        const unsigned short* b = Bp + (size_t)ks * 2048;
        #pragma unroll
        for (int n = 0; n < 4; ++n) {
            bf16x8 bfr = *(const bf16x8*)(b + n * 512);
            acc[n] = __builtin_amdgcn_mfma_f32_16x16x32_bf16(af, bfr, acc[n], 0, 0, 0);
        }
    }
    int col = lane & 15;
    int rbase = m0 + w * 16 + (lane >> 4) * 4;
    float hv[4][4];
    #pragma unroll
    for (int n = 0; n < 4; ++n) {
        float bv = bias[c * biasChanStride + n * 16 + col];
        #pragma unroll
        for (int r = 0; r < 4; ++r) {
            float a = acc[n][r] + bv;
            hv[n][r] = (a > 0.f) ? a + a : a;   // relu(a) + a
        }
    }
    if (EPI == 0) {
        #pragma unroll
        for (int n = 0; n < 4; ++n) {
            #pragma unroll
            for (int r = 0; r < 4; ++r) {
                int rr = rbase + r;
                if (rr < M) Cbf[(size_t)rr * D_ALL + c * 64 + n * 16 + col] = f2bf(hv[n][r]);
            }
        }
    } else {
        // LayerNorm over this channel's 64 dims; row r's 64 values live in
        // acc index n (4) x the 16 lanes sharing lane>>4.
        float sum[4], sq[4];
        #pragma unroll
        for (int r = 0; r < 4; ++r) {
            sum[r] = hv[0][r] + hv[1][r] + hv[2][r] + hv[3][r];
            sq[r] = hv[0][r]*hv[0][r] + hv[1][r]*hv[1][r] + hv[2][r]*hv[2][r] + hv[3][r]*hv[3][r];
        }
        #pragma unroll
        for (int off = 1; off < 16; off <<= 1) {
            #pragma unroll
            for (int r = 0; r < 4; ++r) {
                sum[r] += __shfl_xor(sum[r], off, 64);
                sq[r]  += __shfl_xor(sq[r], off, 64);
            }
        }
        float mu[4], rinv[4];
        #pragma unroll
        for (int r = 0; r < 4; ++r) {
            mu[r] = sum[r] * (1.f / 64.f);
            float var = sq[r] * (1.f / 64.f) - mu[r] * mu[r];
            rinv[r] = rsqrtf(var + 1e-6f);
        }
        #pragma unroll
        for (int n = 0; n < 4; ++n) {
            float gv = gamma[n * 16 + col];
            float bv2 = beta[n * 16 + col];
            #pragma unroll
            for (int r = 0; r < 4; ++r) {
                int rr = rbase + r;
                if (rr < M)
                    outF[(size_t)c * N_NODES * D_H + (size_t)rr * D_H + n * 16 + col] =
                        (hv[n][r] - mu[r]) * rinv[r] * gv + bv2;
            }
        }
    }
}

// ---------------- launch ----------------

extern "C" void kernel_launch(void* const* d_in, const int* in_sizes, int n_in,
                              void* d_out, int out_size, void* d_ws, size_t ws_size,
                              hipStream_t stream) {
    const float* x     = (const float*)d_in[0];
    const int*   edge  = (const int*)d_in[1];
    const float* W0    = (const float*)d_in[3];
    const float* b0    = (const float*)d_in[4];
    const float* Wl    = (const float*)d_in[5];
    const float* bl    = (const float*)d_in[6];
    const float* gamma = (const float*)d_in[7];
    const float* beta  = (const float*)d_in[8];
    float* out = (float*)d_out;

    const int* e_src = edge;            // edge[0]
    const int* e_dst = edge + N_EDGES;  // edge[1]

    char* ws = (char*)d_ws;
    size_t off = 0;
    auto alloc = [&](size_t bytes) -> void* {
        void* p = ws + off;
        off = (off + bytes + 255) & ~(size_t)255;
        return p;
    };
    const int NE_TOT = N_EDGES + N_NODES;   // real edges + self loops
    int*   deg_cnt   = (int*)  alloc(sizeof(int)   * N_NODES);
    int*   cursor    = (int*)  alloc(sizeof(int)   * N_NODES);
    int*   row_start = (int*)  alloc(sizeof(int)   * (N_NODES + 1));
    float* dinv      = (float*)alloc(sizeof(float) * N_NODES);
    int2*  csr_ec    = (int2*) alloc(sizeof(int2)  * NE_TOT);
    unsigned short* x_bf  = (unsigned short*)alloc(sizeof(unsigned short) * (size_t)N_NODES * D_IN);
    unsigned short* W0p   = (unsigned short*)alloc(sizeof(unsigned short) * SZ_C * 4 * 4 * 512);
    unsigned short* Wl0p  = (unsigned short*)alloc(sizeof(unsigned short) * SZ_C * 2 * 4 * 512);
    unsigned short* Wl1p  = (unsigned short*)alloc(sizeof(unsigned short) * SZ_C * 2 * 4 * 512);
    unsigned short* zbuf  = (unsigned short*)alloc(sizeof(unsigned short) * (size_t)N_NODES * D_ALL);
    unsigned short* h_bf  = (unsigned short*)alloc(sizeof(unsigned short) * (size_t)N_NODES * D_ALL);

    const int nb_n = (N_NODES + 255) / 256;
    const int nb_e = (N_EDGES + 255) / 256;

    init_deg_kernel<<<nb_n, 256, 0, stream>>>(deg_cnt, cursor, N_NODES);
    hist_kernel<<<nb_e, 256, 0, stream>>>(e_dst, deg_cnt, N_EDGES);
    dinv_kernel<<<nb_n, 256, 0, stream>>>(deg_cnt, dinv, N_NODES);
    scan_kernel<<<1, 1024, 0, stream>>>(deg_cnt, row_start, N_NODES);
    csr_build_kernel<<<nb_e, 256, 0, stream>>>(e_src, e_dst, row_start, cursor, dinv,
                                               csr_ec, N_EDGES);
    self_edge_kernel<<<nb_n, 256, 0, stream>>>(row_start, dinv, csr_ec, N_NODES);
    // weight packing + x conversion
    pack_b_kernel<<<(SZ_C * 4 * 4 * 512 + 255) / 256, 256, 0, stream>>>(
        W0, D_IN * D_H, 4, W0p, SZ_C * 4 * 4 * 512);
    pack_b_kernel<<<(SZ_C * 2 * 4 * 512 + 255) / 256, 256, 0, stream>>>(
        Wl, 2 * D_H * D_H, 2, Wl0p, SZ_C * 2 * 4 * 512);
    pack_b_kernel<<<(SZ_C * 2 * 4 * 512 + 255) / 256, 256, 0, stream>>>(
        Wl + D_H * D_H, 2 * D_H * D_H, 2, Wl1p, SZ_C * 2 * 4 * 512);
    f2bf_kernel<<<((N_NODES * D_IN / 4) + 255) / 256, 256, 0, stream>>>(
        x, x_bf, N_NODES * D_IN / 4);

    dim3 ggrid((N_NODES + 63) / 64, SZ_C);
    const int agg_grid = N_NODES / 4;  // 12500, exact

    // layer 0: z = agg(x_bf) [N,128]; h = relures(z@W0 + b0) [N,256]
    agg_kernel<D_IN><<<agg_grid, 256, 0, stream>>>(x_bf, row_start, csr_ec, zbuf);
    mfma_gemm_kernel<0><<<ggrid, 256, 0, stream>>>(zbuf, D_IN, 0, W0p, 4,
                                                   b0, 64, h_bf, nullptr, nullptr, nullptr, N_NODES);
    // layer 1: z = agg(h) [N,256]; h = relures(z@Wl0 + bl0)
    agg_kernel<D_ALL><<<agg_grid, 256, 0, stream>>>(h_bf, row_start, csr_ec, zbuf);
    mfma_gemm_kernel<0><<<ggrid, 256, 0, stream>>>(zbuf, D_ALL, 64, Wl0p, 2,
                                                   bl, 2 * 64, h_bf, nullptr, nullptr, nullptr, N_NODES);
    // layer 2: z = agg(h); out = LN(relures(z@Wl1 + bl1)) -> d_out fp32
    agg_kernel<D_ALL><<<agg_grid, 256, 0, stream>>>(h_bf, row_start, csr_ec, zbuf);
    mfma_gemm_kernel<1><<<ggrid, 256, 0, stream>>>(zbuf, D_ALL, 64, Wl1p, 2,
                                                   bl + 64, 2 * 64, nullptr, out, gamma, beta, N_NODES);
}